// Round 1
// 1414.778 us; speedup vs baseline: 1.0004x; 1.0004x over previous
//
#include <hip/hip_runtime.h>
#include <cstdint>
#include <cstddef>

#define T_TOKENS 8192
#define NSLOT (T_TOKENS * 2)
#define HDIM 2048
#define IDIM 2048
#define TWO_I 4096
#define NE 8
#define BMG 256
#define BKG 64
#define NTK 32            // HDIM/BKG == IDIM/BKG
#define MAXTILE 72        // sum ceil(count_e/256) <= 16384/256 + 8

typedef __attribute__((ext_vector_type(8))) short short8;
typedef __attribute__((ext_vector_type(4))) float f32x4;

__device__ __forceinline__ unsigned short f2bf(float f) {
    union { float f; unsigned int u; } v; v.f = f;
    unsigned int u = v.u;
    u += 0x7fffu + ((u >> 16) & 1u);   // RNE
    return (unsigned short)(u >> 16);
}

__device__ __forceinline__ void gload_lds16(const unsigned short* g, unsigned short* l) {
    __builtin_amdgcn_global_load_lds(
        (const __attribute__((address_space(1))) unsigned int*)(g),
        (__attribute__((address_space(3))) unsigned int*)(l), 16, 0, 0);
}

#define LGKM0() do { asm volatile("s_waitcnt lgkmcnt(0)" ::: "memory"); __builtin_amdgcn_sched_barrier(0); } while (0)
#define VM8()   do { asm volatile("s_waitcnt vmcnt(8)"   ::: "memory"); __builtin_amdgcn_sched_barrier(0); } while (0)
#define VM0()   do { asm volatile("s_waitcnt vmcnt(0)"   ::: "memory"); __builtin_amdgcn_sched_barrier(0); } while (0)
#define BAR()   __builtin_amdgcn_s_barrier()

// ---------------- gating: logits -> top2 -> softmax ----------------
__global__ __launch_bounds__(256) void k_gate(const float* __restrict__ x,
                                              const float* __restrict__ gw,
                                              const float* __restrict__ gb,
                                              int* __restrict__ tok_e,
                                              float* __restrict__ tok_w,
                                              int* __restrict__ counts) {
    __shared__ float gwl[NE * HDIM];   // 64KB
    for (int i = threadIdx.x; i < NE * HDIM / 4; i += 256)
        ((float4*)gwl)[i] = ((const float4*)gw)[i];
    __syncthreads();
    int wid = threadIdx.x >> 6, lane = threadIdx.x & 63;
    int gwave = blockIdx.x * 4 + wid;            // 1024 waves
    for (int t = gwave; t < T_TOKENS; t += 1024) {
        float acc[NE];
#pragma unroll
        for (int e = 0; e < NE; e++) acc[e] = 0.f;
        const float4* xr = (const float4*)(x + (size_t)t * HDIM);
#pragma unroll
        for (int i0 = 0; i0 < HDIM / 4 / 64; i0++) {
            int i = i0 * 64 + lane;
            float4 xv = xr[i];
#pragma unroll
            for (int e = 0; e < NE; e++) {
                float4 gv = ((const float4*)gwl)[e * (HDIM / 4) + i];
                acc[e] += xv.x * gv.x + xv.y * gv.y + xv.z * gv.z + xv.w * gv.w;
            }
        }
#pragma unroll
        for (int e = 0; e < NE; e++) {
#pragma unroll
            for (int off = 32; off; off >>= 1) acc[e] += __shfl_xor(acc[e], off);
        }
        if (lane == 0) {
            float lg[NE];
#pragma unroll
            for (int e = 0; e < NE; e++) lg[e] = acc[e] + gb[e];
            int i0 = 0;
#pragma unroll
            for (int e = 1; e < NE; e++) if (lg[e] > lg[i0]) i0 = e;
            int i1 = (i0 == 0) ? 1 : 0;
#pragma unroll
            for (int e = 0; e < NE; e++) if (e != i0 && lg[e] > lg[i1]) i1 = e;
            float e1 = __expf(lg[i1] - lg[i0]);
            float s = 1.f + e1;
            tok_e[t * 2 + 0] = i0; tok_e[t * 2 + 1] = i1;
            tok_w[t * 2 + 0] = 1.f / s; tok_w[t * 2 + 1] = e1 / s;
            atomicAdd(&counts[i0], 1);
            atomicAdd(&counts[i1], 1);
        }
    }
}

__global__ void k_prefix(const int* __restrict__ counts, int* __restrict__ base,
                         int* __restrict__ tb) {
    if (threadIdx.x == 0) {
        int b = 0, t = 0;
        for (int e = 0; e < NE; e++) {
            base[e] = b; tb[e] = t;
            b += counts[e];
            t += (counts[e] + BMG - 1) / BMG;
        }
        base[NE] = b; tb[NE] = t;
    }
}

__global__ __launch_bounds__(256) void k_scatter(const int* __restrict__ tok_e,
                                                 const float* __restrict__ tok_w,
                                                 const int* __restrict__ base,
                                                 int* __restrict__ cursor,
                                                 int* __restrict__ slot_tok,
                                                 int* __restrict__ slot_of) {
    int t = blockIdx.x * 256 + threadIdx.x;
    if (t >= T_TOKENS) return;
#pragma unroll
    for (int k = 0; k < 2; k++) {
        int e = tok_e[t * 2 + k];
        int p = atomicAdd(&cursor[e], 1);
        int s = base[e] + p;
        slot_tok[s] = t;
        slot_of[t * 2 + k] = s;
    }
}

__global__ __launch_bounds__(256) void k_convert(const float* __restrict__ src,
                                                 unsigned short* __restrict__ dst) {
    int i = blockIdx.x * 256 + threadIdx.x;   // one float4 per thread
    float4 v = ((const float4*)src)[i];
    union { unsigned short s[4]; uint2 u; } o;
    o.s[0] = f2bf(v.x); o.s[1] = f2bf(v.y); o.s[2] = f2bf(v.z); o.s[3] = f2bf(v.w);
    ((uint2*)dst)[i] = o.u;
}

// ---------------- GEMM1: 256x128(y-cols) tile, BK=64, 8 waves, counted-vmcnt pipeline ----------------
// B-tile = 256 W1 rows packed per-wave: wave wc owns LDS B rows [wc*64, wc*64+64):
//   rows 0..31 of the span = GLU rows 2*(c0+wc*32+idx), rows 32..63 = LIN rows +1.
__global__ __launch_bounds__(512, 2) void k_gemm1(const unsigned short* __restrict__ Xb,
                                                  const unsigned short* __restrict__ W1b,
                                                  const float* __restrict__ b1,
                                                  const int* __restrict__ slot_tok,
                                                  const int* __restrict__ base,
                                                  const int* __restrict__ tb,
                                                  unsigned short* __restrict__ Y) {
    int g = blockIdx.x >> 4;
    int nt = blockIdx.x & 15;
    if (g >= tb[NE]) return;
    int e = 0;
    while (tb[e + 1] <= g) e++;
    int mt = g - tb[e];
    int slot0 = base[e] + mt * BMG;
    int mrows = base[e + 1] - base[e] - mt * BMG; if (mrows > BMG) mrows = BMG;

    __shared__ unsigned short As[2][BMG * BKG];   // 64KB
    __shared__ unsigned short Bs[2][BMG * BKG];   // 64KB
    __shared__ int stok[BMG];

    int tid = threadIdx.x;
    if (tid < BMG) {
        int s = slot0 + tid; if (s > NSLOT - 1) s = NSLOT - 1;
        stok[tid] = slot_tok[s];
    }
    __syncthreads();

    int wid = tid >> 6, lane = tid & 63;
    int c0 = nt * 128;
    const unsigned short* W1e = W1b + (size_t)e * TWO_I * HDIM;

    // staging: thread -> LDS chunk (row = j*64 + tid>>3, chunkpos = tid&7); swizzled global chunk
    int srow = tid >> 3;
    int scp = ((tid & 7) ^ (srow & 7)) * 8;
    unsigned int gaoff[4], gboff[4];
#pragma unroll
    for (int j = 0; j < 4; j++) {
        int row = j * 64 + srow;
        gaoff[j] = (unsigned int)stok[row] * HDIM + scp;
        int wcp = row >> 6, lr = row & 63, q = lr >> 5, idx = lr & 31;
        int w1r = 2 * (c0 + 32 * wcp + idx) + q;
        gboff[j] = (unsigned int)w1r * HDIM + scp;
    }
    unsigned short* laA = &As[0][tid * 8];
    unsigned short* laB = &Bs[0][tid * 8];

    auto STAGE = [&](int cbuf, int kk) {
#pragma unroll
        for (int j = 0; j < 4; j++)
            gload_lds16(Xb + gaoff[j] + kk, laA + cbuf * (BMG * BKG) + j * 4096);
#pragma unroll
        for (int j = 0; j < 4; j++)
            gload_lds16(W1e + gboff[j] + kk, laB + cbuf * (BMG * BKG) + j * 4096);
    };

    int wr = wid & 1, wc = wid >> 1;
    int fr = lane & 15, kq = lane >> 4;
    int f7 = fr & 7;
    // element offsets into a [256][64] tile, chunk-swizzled: elem = row*64 + (kchunk^(row&7))*8
    int aoff0 = (wr * 128 + fr) * BKG + ((0 + kq) ^ f7) * 8;
    int aoff1 = (wr * 128 + fr) * BKG + ((4 + kq) ^ f7) * 8;
    int boff0 = (wc * 64 + fr) * BKG + ((0 + kq) ^ f7) * 8;
    int boff1 = (wc * 64 + fr) * BKG + ((4 + kq) ^ f7) * 8;

    f32x4 acc[8][4];
#pragma unroll
    for (int mi = 0; mi < 8; mi++)
#pragma unroll
        for (int ni = 0; ni < 4; ni++) acc[mi][ni] = (f32x4)0.f;

    STAGE(0, 0);
    STAGE(1, BKG);
    VM8(); BAR();        // T0 landed everywhere; T1 in flight

    for (int t = 0; t < NTK; t++) {
        int cb = t & 1;
        const unsigned short* Ac = &As[0][0] + cb * (BMG * BKG);
        const unsigned short* Bc = &Bs[0][0] + cb * (BMG * BKG);

        short8 a0[8], bb0[4];
#pragma unroll
        for (int mi = 0; mi < 8; mi++) a0[mi] = *(const short8*)(Ac + aoff0 + mi * (16 * BKG));
#pragma unroll
        for (int ni = 0; ni < 4; ni++) bb0[ni] = *(const short8*)(Bc + boff0 + ni * (16 * BKG));
        __builtin_amdgcn_s_setprio(1);
#pragma unroll
        for (int mi = 0; mi < 8; mi++)
#pragma unroll
            for (int ni = 0; ni < 4; ni++)
                acc[mi][ni] = __builtin_amdgcn_mfma_f32_16x16x32_bf16(a0[mi], bb0[ni], acc[mi][ni], 0, 0, 0);
        __builtin_amdgcn_s_setprio(0);

        short8 a1[8], bb1[4];
#pragma unroll
        for (int mi = 0; mi < 8; mi++) a1[mi] = *(const short8*)(Ac + aoff1 + mi * (16 * BKG));
#pragma unroll
        for (int ni = 0; ni < 4; ni++) bb1[ni] = *(const short8*)(Bc + boff1 + ni * (16 * BKG));
        LGKM0();
        BAR();                        // all waves done reading buf[cb]
        if (t + 2 < NTK) {
            STAGE(cb, (t + 2) * BKG); // overwrite buf[cb] with tile t+2
            VM8();                    // drain T(t+1); T(t+2) stays in flight
        } else {
            VM0();                    // tail: drain T(t+1)
        }
        __builtin_amdgcn_s_setprio(1);
#pragma unroll
        for (int mi = 0; mi < 8; mi++)
#pragma unroll
            for (int ni = 0; ni < 4; ni++)
                acc[mi][ni] = __builtin_amdgcn_mfma_f32_16x16x32_bf16(a1[mi], bb1[ni], acc[mi][ni], 0, 0, 0);
        __builtin_amdgcn_s_setprio(0);
        BAR();                        // T(t+1) landed everywhere before next tile reads
    }

    // epilogue: SwiGLU. ni 0/1 = GLU cols, ni 2/3 = matching LIN cols.
    const float* b1e = b1 + (size_t)e * TWO_I;
#pragma unroll
    for (int ni = 0; ni < 2; ni++) {
        int ycol = c0 + wc * 32 + ni * 16 + fr;
        float bg_ = b1e[2 * ycol], bl_ = b1e[2 * ycol + 1];
#pragma unroll
        for (int mi = 0; mi < 8; mi++) {
#pragma unroll
            for (int r = 0; r < 4; r++) {
                int m = wr * 128 + mi * 16 + kq * 4 + r;
                if (m < mrows) {
                    float gv = acc[mi][ni][r] + bg_;
                    float lv = acc[mi][ni + 2][r] + bl_;
                    float yv = gv * (1.f / (1.f + __expf(-1.702f * gv))) * (lv + 1.f);
                    Y[(size_t)(slot0 + m) * IDIM + ycol] = f2bf(yv);
                }
            }
        }
    }
}

// ---------------- GEMM2: 256x256 tile, same pipeline; Y2 = Y@w2^T + b2 ----------------
__global__ __launch_bounds__(512, 2) void k_gemm2(const unsigned short* __restrict__ Y,
                                                  const unsigned short* __restrict__ W2b,
                                                  const float* __restrict__ b2,
                                                  const int* __restrict__ base,
                                                  const int* __restrict__ tb,
                                                  float* __restrict__ Y2) {
    int g = blockIdx.x >> 3;
    int nt = blockIdx.x & 7;
    if (g >= tb[NE]) return;
    int e = 0;
    while (tb[e + 1] <= g) e++;
    int mt = g - tb[e];
    int slot0 = base[e] + mt * BMG;
    int mrows = base[e + 1] - base[e] - mt * BMG; if (mrows > BMG) mrows = BMG;

    __shared__ unsigned short As[2][BMG * BKG];   // 64KB
    __shared__ unsigned short Bs[2][BMG * BKG];   // 64KB

    int tid = threadIdx.x;
    int wid = tid >> 6, lane = tid & 63;
    int n0 = nt * 256;
    const unsigned short* W2e = W2b + (size_t)e * HDIM * IDIM;

    int srow = tid >> 3;
    int scp = ((tid & 7) ^ (srow & 7)) * 8;
    unsigned int gaoff[4], gboff[4];
#pragma unroll
    for (int j = 0; j < 4; j++) {
        int row = j * 64 + srow;
        int s = slot0 + row; if (s > NSLOT - 1) s = NSLOT - 1;
        gaoff[j] = (unsigned int)s * IDIM + scp;
        gboff[j] = (unsigned int)(n0 + row) * IDIM + scp;
    }
    unsigned short* laA = &As[0][tid * 8];
    unsigned short* laB = &Bs[0][tid * 8];

    auto STAGE = [&](int cbuf, int kk) {
#pragma unroll
        for (int j = 0; j < 4; j++)
            gload_lds16(Y + gaoff[j] + kk, laA + cbuf * (BMG * BKG) + j * 4096);
#pragma unroll
        for (int j = 0; j < 4; j++)
            gload_lds16(W2e + gboff[j] + kk, laB + cbuf * (BMG * BKG) + j * 4096);
    };

    int wr = wid & 1, wc = wid >> 1;
    int fr = lane & 15, kq = lane >> 4;
    int f7 = fr & 7;
    int aoff0 = (wr * 128 + fr) * BKG + ((0 + kq) ^ f7) * 8;
    int aoff1 = (wr * 128 + fr) * BKG + ((4 + kq) ^ f7) * 8;
    int boff0 = (wc * 64 + fr) * BKG + ((0 + kq) ^ f7) * 8;
    int boff1 = (wc * 64 + fr) * BKG + ((4 + kq) ^ f7) * 8;

    f32x4 acc[8][4];
#pragma unroll
    for (int mi = 0; mi < 8; mi++)
#pragma unroll
        for (int ni = 0; ni < 4; ni++) acc[mi][ni] = (f32x4)0.f;

    STAGE(0, 0);
    STAGE(1, BKG);
    VM8(); BAR();

    for (int t = 0; t < NTK; t++) {
        int cb = t & 1;
        const unsigned short* Ac = &As[0][0] + cb * (BMG * BKG);
        const unsigned short* Bc = &Bs[0][0] + cb * (BMG * BKG);

        short8 a0[8], bb0[4];
#pragma unroll
        for (int mi = 0; mi < 8; mi++) a0[mi] = *(const short8*)(Ac + aoff0 + mi * (16 * BKG));
#pragma unroll
        for (int ni = 0; ni < 4; ni++) bb0[ni] = *(const short8*)(Bc + boff0 + ni * (16 * BKG));
        __builtin_amdgcn_s_setprio(1);
#pragma unroll
        for (int mi = 0; mi < 8; mi++)
#pragma unroll
            for (int ni = 0; ni < 4; ni++)
                acc[mi][ni] = __builtin_amdgcn_mfma_f32_16x16x32_bf16(a0[mi], bb0[ni], acc[mi][ni], 0, 0, 0);
        __builtin_amdgcn_s_setprio(0);

        short8 a1[8], bb1[4];
#pragma unroll
        for (int mi = 0; mi < 8; mi++) a1[mi] = *(const short8*)(Ac + aoff1 + mi * (16 * BKG));
#pragma unroll
        for (int ni = 0; ni < 4; ni++) bb1[ni] = *(const short8*)(Bc + boff1 + ni * (16 * BKG));
        LGKM0();
        BAR();
        if (t + 2 < NTK) {
            STAGE(cb, (t + 2) * BKG);
            VM8();
        } else {
            VM0();
        }
        __builtin_amdgcn_s_setprio(1);
#pragma unroll
        for (int mi = 0; mi < 8; mi++)
#pragma unroll
            for (int ni = 0; ni < 4; ni++)
                acc[mi][ni] = __builtin_amdgcn_mfma_f32_16x16x32_bf16(a1[mi], bb1[ni], acc[mi][ni], 0, 0, 0);
        __builtin_amdgcn_s_setprio(0);
        BAR();
    }

    const float* b2e = b2 + (size_t)e * HDIM;
#pragma unroll
    for (int ni = 0; ni < 4; ni++) {
        int col = n0 + wc * 64 + ni * 16 + fr;
        float bv = b2e[col];
#pragma unroll
        for (int mi = 0; mi < 8; mi++) {
#pragma unroll
            for (int r = 0; r < 4; r++) {
                int m = wr * 128 + mi * 16 + kq * 4 + r;
                if (m < mrows)
                    Y2[(size_t)(slot0 + m) * HDIM + col] = acc[mi][ni][r] + bv;
            }
        }
    }
}

// ---------------- combine: out[t] = w0*Y2[s0] + w1*Y2[s1] ----------------
__global__ __launch_bounds__(256) void k_combine(const float* __restrict__ Y2,
                                                 const int* __restrict__ slot_of,
                                                 const float* __restrict__ tok_w,
                                                 float* __restrict__ out) {
    int t = blockIdx.x;
    int s0 = slot_of[t * 2], s1 = slot_of[t * 2 + 1];
    float w0 = tok_w[t * 2], w1 = tok_w[t * 2 + 1];
    const float4* r0 = (const float4*)(Y2 + (size_t)s0 * HDIM);
    const float4* r1 = (const float4*)(Y2 + (size_t)s1 * HDIM);
    float4* o = (float4*)(out + (size_t)t * HDIM);
#pragma unroll
    for (int it = 0; it < HDIM / 4 / 256; it++) {
        int i = it * 256 + threadIdx.x;
        float4 a = r0[i], b = r1[i];
        float4 v;
        v.x = w0 * a.x + w1 * b.x;
        v.y = w0 * a.y + w1 * b.y;
        v.z = w0 * a.z + w1 * b.z;
        v.w = w0 * a.w + w1 * b.w;
        o[i] = v;
    }
}

extern "C" void kernel_launch(void* const* d_in, const int* in_sizes, int n_in,
                              void* d_out, int out_size, void* d_ws, size_t ws_size,
                              hipStream_t stream) {
    const float* x  = (const float*)d_in[0];
    const float* gw = (const float*)d_in[1];
    const float* gb = (const float*)d_in[2];
    const float* w1 = (const float*)d_in[3];
    const float* b1 = (const float*)d_in[4];
    const float* w2 = (const float*)d_in[5];
    const float* b2 = (const float*)d_in[6];
    float* out = (float*)d_out;

    char* w = (char*)d_ws;
    int* counts = (int*)w;          // 8
    int* cursor = counts + 8;       // 8
    int* base   = counts + 16;      // 9
    int* tb     = counts + 32;      // 9
    int* tok_e    = (int*)(w + 4096);
    float* tok_w  = (float*)(w + 4096 + 65536);
    int* slot_tok = (int*)(w + 4096 + 131072);
    int* slot_of  = (int*)(w + 4096 + 196608);

    size_t off = 1 << 20;
    unsigned short* Xb  = (unsigned short*)(w + off); off += (size_t)T_TOKENS * HDIM * 2;   // 33.5 MB
    unsigned short* Y   = (unsigned short*)(w + off); off += (size_t)NSLOT * IDIM * 2;      // 67 MB
    unsigned short* W1b = (unsigned short*)(w + off); off += (size_t)NE * TWO_I * HDIM * 2; // 134 MB
    unsigned short* W2b = (unsigned short*)(w + off); off += (size_t)NE * HDIM * IDIM * 2;  // 67 MB
    float*          Y2  = (float*)(w + off);          off += (size_t)NSLOT * HDIM * 4;      // 134 MB

    hipMemsetAsync(d_ws, 0, 256, stream);

    hipLaunchKernelGGL(k_gate, dim3(256), dim3(256), 0, stream, x, gw, gb, tok_e, tok_w, counts);
    hipLaunchKernelGGL(k_convert, dim3(T_TOKENS * HDIM / 4 / 256), dim3(256), 0, stream, x, Xb);
    hipLaunchKernelGGL(k_convert, dim3(NE * TWO_I * HDIM / 4 / 256), dim3(256), 0, stream, w1, W1b);
    hipLaunchKernelGGL(k_convert, dim3(NE * HDIM * IDIM / 4 / 256), dim3(256), 0, stream, w2, W2b);
    hipLaunchKernelGGL(k_prefix, dim3(1), dim3(64), 0, stream, counts, base, tb);
    hipLaunchKernelGGL(k_scatter, dim3(T_TOKENS / 256), dim3(256), 0, stream,
                       tok_e, tok_w, base, cursor, slot_tok, slot_of);
    hipLaunchKernelGGL(k_gemm1, dim3(MAXTILE * 16), dim3(512), 0, stream,
                       Xb, W1b, b1, slot_tok, base, tb, Y);
    hipLaunchKernelGGL(k_gemm2, dim3(MAXTILE * 8), dim3(512), 0, stream,
                       Y, W2b, b2, base, tb, Y2);
    hipLaunchKernelGGL(k_combine, dim3(T_TOKENS), dim3(256), 0, stream,
                       Y2, slot_of, tok_w, out);
}